// Round 16
// baseline (505.358 us; speedup 1.0000x reference)
//
#include <hip/hip_runtime.h>

#define B_ 512
#define T_ 512
#define V_ 96
#define H_ 128
#define K2F 2.8853900817779268f   // 2*log2(e): exp(2s) == exp2(K2F*s)

typedef _Float16 half8 __attribute__((ext_vector_type(8)));
typedef float    f32x4 __attribute__((ext_vector_type(4)));

// Pass 1a: recover the one-hot index per (b,t). x is exactly {0.0, 1.0}.
__global__ __launch_bounds__(256) void onehot_idx_kernel(
    const float4* __restrict__ x4, int n4, int* __restrict__ idx)
{
    int stride = gridDim.x * blockDim.x;
    for (int e4 = blockIdx.x * blockDim.x + threadIdx.x; e4 < n4; e4 += stride) {
        float4 v = x4[e4];
        int base = e4 * 4;
        if (v.x > 0.5f) idx[(base + 0) / V_] = (base + 0) % V_;
        if (v.y > 0.5f) idx[(base + 1) / V_] = (base + 1) % V_;
        if (v.z > 0.5f) idx[(base + 2) / V_] = (base + 2) % V_;
        if (v.w > 0.5f) idx[(base + 3) / V_] = (base + 3) % V_;
    }
}

// Pass 1b: xwg[v][u'] with u' = (u&15)*8 + (u>>4): per-step C-init gather is
// 2 coalesced float4 loads per row. Bias-folded, K2F-scaled.
__global__ __launch_bounds__(256) void build_xwg_kernel(
    const float* __restrict__ W_ih, const float* __restrict__ b_ih,
    const float* __restrict__ b_hh, float* __restrict__ xwg)
{
    int e = blockIdx.x * 256 + threadIdx.x;
    if (e < V_ * H_) {
        int v = e >> 7, up = e & 127;
        int u = (up & 7) * 16 + (up >> 3);     // invert u' mapping
        xwg[e] = (W_ih[u * V_ + v] + b_ih[u] + b_hh[u]) * K2F;
    }
}

// Pass 1c: B-fragments for the recurrence MFMA (K2F pre-scaled, f16).
// Frag (ks,nt): lane holds B[k=(lane>>4)*8+reg][n=nt*16+(lane&15)],
// k -> input unit = ks*32 + (lane>>4)*8 + reg (contiguous-8, symmetric w/ A).
__global__ __launch_bounds__(256) void build_wB_kernel(
    const float* __restrict__ W_hh, _Float16* __restrict__ wB)
{
    int e = blockIdx.x * 256 + threadIdx.x;     // 4ks*8nt*64lane*8reg = 16384
    if (e < 16384) {
        int reg = e & 7, lane = (e >> 3) & 63, nt = (e >> 9) & 7, ks = e >> 12;
        int unit = ks * 32 + (lane >> 4) * 8 + reg;
        int n    = nt * 16 + (lane & 15);
        wB[e] = (_Float16)(K2F * W_hh[n * H_ + unit]);
    }
}

// Pass 1d: B-fragments for the fc epilogue (unscaled W_fc, f16). 6 n-tiles.
__global__ __launch_bounds__(256) void build_wBfc_kernel(
    const float* __restrict__ W_fc, _Float16* __restrict__ wBfc)
{
    int e = blockIdx.x * 256 + threadIdx.x;     // 4*6*64*8 = 12288
    if (e < 12288) {
        int reg = e & 7, lane = (e >> 3) & 63;
        int nt = (e >> 9) % 6, ks = e / 3072;
        int unit = ks * 32 + (lane >> 4) * 8 + reg;
        int n    = nt * 16 + (lane & 15);
        wBfc[e] = (_Float16)W_fc[n * H_ + unit];
    }
}

// Pass 2: ONE WAVE per 16 batch rows (grid=32), no barriers.
// R15 failed (absmax 0.164) from a memory-model hazard, not layout: h state
// was read via ull casts (TBAA says "no alias" with the _Float16 stores) at
// LOOP-INVARIANT addresses -> compiler free to hoist stale reads across the
// loop-carried RAW. Fix: double-buffered hs + __builtin_memcpy loads
// (char-family TBAA aliases everything) + sched_barrier(0) per iteration.
__global__ __launch_bounds__(64, 1) void rnn_mfma_kernel(
    const uint4* __restrict__ wBg, const uint4* __restrict__ wBfcg,
    const float* __restrict__ xwg, const int* __restrict__ idx,
    const float* __restrict__ b_fc, float* __restrict__ out)
{
    const int bb = blockIdx.x;         // rows 16*bb .. 16*bb+15
    const int l  = threadIdx.x;
    const int lo = l & 15, g = l >> 4;

    __shared__ _Float16      hs[2][16][132];      // dbl-buffered h, +4 pad
    __shared__ unsigned char idxT[(T_ + 2) * 16]; // [t][row] char ids

    for (int e = l; e < 16 * T_; e += 64) {
        int row = e >> 9, t = e & 511;
        idxT[t * 16 + row] = (unsigned char)idx[(bb * 16 + row) * T_ + t];
    }
    if (l < 32) idxT[T_ * 16 + l] = 0;            // pad for t+2 lookahead
    for (int e = l; e < 16 * 132; e += 64)        // typed zero-init of buf 0
        hs[0][e / 132][e % 132] = (_Float16)0.f;

    // recurrence B-frags: 32 x uint4 = 128 regs, loaded ONCE
    uint4 wb[4][8];
    #pragma unroll
    for (int ks = 0; ks < 4; ++ks)
        #pragma unroll
        for (int nt = 0; nt < 8; ++nt)
            wb[ks][nt] = wBg[(ks * 8 + nt) * 64 + l];

    // prologue: gather xw for t=0; read ids for t=1
    float4 xlo[4], xhi[4];
    unsigned idw;
    __builtin_memcpy(&idw, &idxT[0 * 16 + 4 * g], 4);
    #pragma unroll
    for (int j = 0; j < 4; ++j) {
        int id = (idw >> (8 * j)) & 255;
        const float* p = xwg + id * 128 + lo * 8;
        xlo[j] = *(const float4*)p;
        xhi[j] = *(const float4*)(p + 4);
    }
    __builtin_memcpy(&idw, &idxT[1 * 16 + 4 * g], 4);

    int cur = 0;
    #pragma clang loop unroll(disable)
    for (int t = 0; t < T_; ++t) {
        // A-frags: h_{t-1} row-major; memcpy = may-alias load (RAW modeled)
        half8 aF[4];
        #pragma unroll
        for (int ks = 0; ks < 4; ++ks)
            __builtin_memcpy(&aF[ks], &hs[cur][lo][ks * 32 + g * 8], 16);

        // C-init: acc[nt][j] = xw[id_rowj][unit = nt*16+lo]
        f32x4 acc[8];
        #pragma unroll
        for (int nt = 0; nt < 4; ++nt)
            acc[nt] = (f32x4){xlo[0][nt], xlo[1][nt], xlo[2][nt], xlo[3][nt]};
        #pragma unroll
        for (int nt = 0; nt < 4; ++nt)
            acc[nt + 4] = (f32x4){xhi[0][nt], xhi[1][nt], xhi[2][nt], xhi[3][nt]};
        // prefetch next step's gathers (xlo/xhi free now; full step of slack)
        #pragma unroll
        for (int j = 0; j < 4; ++j) {
            int id = (idw >> (8 * j)) & 255;
            const float* p = xwg + id * 128 + lo * 8;
            xlo[j] = *(const float4*)p;
            xhi[j] = *(const float4*)(p + 4);
        }
        __builtin_memcpy(&idw, &idxT[(t + 2) * 16 + 4 * g], 4);

        // 32 MFMAs: D = K2F*(h @ Whh^T) + xw  == exp2 argument directly
        #pragma unroll
        for (int ks = 0; ks < 4; ++ks) {
            #pragma unroll
            for (int nt = 0; nt < 8; ++nt) {
                union { uint4 u; half8 h; } ub; ub.u = wb[ks][nt];
                acc[nt] = __builtin_amdgcn_mfma_f32_16x16x32_f16(
                              aF[ks], ub.h, acc[nt], 0, 0, 0);
            }
        }
        // tanh(s) = 1 - 2/(exp2(D)+1); typed f16 stores into the OTHER buffer
        #pragma unroll
        for (int nt = 0; nt < 8; ++nt) {
            #pragma unroll
            for (int j = 0; j < 4; ++j) {
                float E  = __builtin_amdgcn_exp2f(acc[nt][j]);
                float hv = 1.0f - 2.0f * __builtin_amdgcn_rcpf(E + 1.0f);
                hs[cur ^ 1][4 * g + j][nt * 16 + lo] = (_Float16)hv;
            }
        }
        cur ^= 1;
        __builtin_amdgcn_sched_barrier(0);   // wall: stores(t) || loads(t+1)
    }

    // fc epilogue: out[m][n] = h_T @ W_fc^T + b_fc  via 24 MFMAs
    half8 aE[4];
    #pragma unroll
    for (int ks = 0; ks < 4; ++ks)
        __builtin_memcpy(&aE[ks], &hs[cur][lo][ks * 32 + g * 8], 16);
    #pragma unroll
    for (int nt = 0; nt < 6; ++nt) {
        float bf = b_fc[nt * 16 + lo];
        f32x4 acc = (f32x4){bf, bf, bf, bf};
        #pragma unroll
        for (int ks = 0; ks < 4; ++ks) {
            union { uint4 u; half8 h; } ub;
            ub.u = wBfcg[(ks * 6 + nt) * 64 + l];
            acc = __builtin_amdgcn_mfma_f32_16x16x32_f16(aE[ks], ub.h, acc, 0, 0, 0);
        }
        #pragma unroll
        for (int j = 0; j < 4; ++j)
            out[(bb * 16 + 4 * g + j) * V_ + nt * 16 + lo] = acc[j];
    }
}

extern "C" void kernel_launch(void* const* d_in, const int* in_sizes, int n_in,
                              void* d_out, int out_size, void* d_ws, size_t ws_size,
                              hipStream_t stream)
{
    const float* x    = (const float*)d_in[0];
    const float* W_ih = (const float*)d_in[1];
    const float* b_ih = (const float*)d_in[2];
    const float* W_hh = (const float*)d_in[3];
    const float* b_hh = (const float*)d_in[4];
    const float* W_fc = (const float*)d_in[5];
    const float* b_fc = (const float*)d_in[6];
    float* out = (float*)d_out;

    char* ws = (char*)d_ws;
    int*      idx  = (int*)ws;                               // 1 MiB
    float*    xwg  = (float*)(ws + (size_t)B_ * T_ * 4);     // 48 KiB
    _Float16* wB   = (_Float16*)((char*)xwg + V_ * H_ * 4);  // 32 KiB
    _Float16* wBfc = (_Float16*)((char*)wB + 16384 * 2);     // 24 KiB

    const int n4 = (B_ * T_ * V_) / 4;
    hipLaunchKernelGGL(onehot_idx_kernel, dim3(2048), dim3(256), 0, stream,
                       (const float4*)x, n4, idx);
    hipLaunchKernelGGL(build_xwg_kernel, dim3((V_ * H_ + 255) / 256), dim3(256),
                       0, stream, W_ih, b_ih, b_hh, xwg);
    hipLaunchKernelGGL(build_wB_kernel, dim3(64), dim3(256), 0, stream, W_hh, wB);
    hipLaunchKernelGGL(build_wBfc_kernel, dim3(48), dim3(256), 0, stream, W_fc, wBfc);
    hipLaunchKernelGGL(rnn_mfma_kernel, dim3(B_ / 16), dim3(64), 0, stream,
                       (const uint4*)wB, (const uint4*)wBfc, xwg, idx, b_fc, out);
}

// Round 17
// 233.025 us; speedup vs baseline: 2.1687x; 2.1687x over previous
//
#include <hip/hip_runtime.h>

#define B_ 512
#define T_ 512
#define V_ 96
#define H_ 128
#define K2F 2.8853900817779268f   // 2*log2(e): exp(2s) == exp2(K2F*s)

typedef _Float16 half8 __attribute__((ext_vector_type(8)));
typedef float    f32x4 __attribute__((ext_vector_type(4)));

// Pass 1a: recover the one-hot index per (b,t). x is exactly {0.0, 1.0}.
__global__ __launch_bounds__(256) void onehot_idx_kernel(
    const float4* __restrict__ x4, int n4, int* __restrict__ idx)
{
    int stride = gridDim.x * blockDim.x;
    for (int e4 = blockIdx.x * blockDim.x + threadIdx.x; e4 < n4; e4 += stride) {
        float4 v = x4[e4];
        int base = e4 * 4;
        if (v.x > 0.5f) idx[(base + 0) / V_] = (base + 0) % V_;
        if (v.y > 0.5f) idx[(base + 1) / V_] = (base + 1) % V_;
        if (v.z > 0.5f) idx[(base + 2) / V_] = (base + 2) % V_;
        if (v.w > 0.5f) idx[(base + 3) / V_] = (base + 3) % V_;
    }
}

// Pass 1b (R16-VERIFIED): xwg[v][u'] with u' = (u&15)*8 + (u>>4) inverse
// u = (u'&7)*16 + (u'>>3): unit nt*16+lo sits at position lo*8+nt, so a
// lane's per-row xw pair (q=0,1 of NT=2w+q) is one aligned float2.
__global__ __launch_bounds__(256) void build_xwg_kernel(
    const float* __restrict__ W_ih, const float* __restrict__ b_ih,
    const float* __restrict__ b_hh, float* __restrict__ xwg)
{
    int e = blockIdx.x * 256 + threadIdx.x;
    if (e < V_ * H_) {
        int v = e >> 7, up = e & 127;
        int u = (up & 7) * 16 + (up >> 3);
        xwg[e] = (W_ih[u * V_ + v] + b_ih[u] + b_hh[u]) * K2F;
    }
}

// Pass 1c (R16-VERIFIED): recurrence B-frags, K2F pre-scaled f16.
__global__ __launch_bounds__(256) void build_wB_kernel(
    const float* __restrict__ W_hh, _Float16* __restrict__ wB)
{
    int e = blockIdx.x * 256 + threadIdx.x;     // 4ks*8nt*64lane*8reg = 16384
    if (e < 16384) {
        int reg = e & 7, lane = (e >> 3) & 63, nt = (e >> 9) & 7, ks = e >> 12;
        int unit = ks * 32 + (lane >> 4) * 8 + reg;
        int n    = nt * 16 + (lane & 15);
        wB[e] = (_Float16)(K2F * W_hh[n * H_ + unit]);
    }
}

// Pass 1d (R16-VERIFIED): fc B-frags (unscaled W_fc, f16), 6 n-tiles.
__global__ __launch_bounds__(256) void build_wBfc_kernel(
    const float* __restrict__ W_fc, _Float16* __restrict__ wBfc)
{
    int e = blockIdx.x * 256 + threadIdx.x;     // 4*6*64*8 = 12288
    if (e < 12288) {
        int reg = e & 7, lane = (e >> 3) & 63;
        int nt = (e >> 9) % 6, ks = e / 3072;
        int unit = ks * 32 + (lane >> 4) * 8 + reg;
        int n    = nt * 16 + (lane & 15);
        wBfc[e] = (_Float16)W_fc[n * H_ + unit];
    }
}

// Pass 2: 4 WAVES per block, one block per 16 batch rows (grid=32).
// Wave w owns output units [32w, 32w+32) = MFMA n-tiles {2w, 2w+1}:
//   8 MFMAs/step (vs 32) and -- the R16 bottleneck -- the tanh tail
//   shrinks 4x to 8 exp2 + 8 rcp + 8 b16-stores per lane.
// One __syncthreads per step (h is produced across waves).
// xw is added POST-MFMA (not C-init): kills the 4x4 register transpose
// and gives the global float2 prefetch a full step of extra slack.
__global__ __launch_bounds__(256, 1) void rnn_mfma4_kernel(
    const uint4* __restrict__ wBg, const uint4* __restrict__ wBfcg,
    const float* __restrict__ xwg, const int* __restrict__ idx,
    const float* __restrict__ b_fc, float* __restrict__ out)
{
    const int bb  = blockIdx.x;        // rows 16*bb .. 16*bb+15
    const int tid = threadIdx.x;
    const int w   = tid >> 6;          // wave 0..3 -> n-tiles {2w, 2w+1}
    const int l   = tid & 63;
    const int lo  = l & 15, g = l >> 4;

    __shared__ _Float16      hs[2][16][136];      // dbl-buffered h, +8 pad (16B rows)
    __shared__ unsigned char idxT[(T_ + 2) * 16]; // [t][row] char ids

    for (int e = tid; e < 16 * T_; e += 256) {
        int row = e >> 9, t = e & 511;
        idxT[t * 16 + row] = (unsigned char)idx[(bb * 16 + row) * T_ + t];
    }
    if (tid < 32) idxT[T_ * 16 + tid] = 0;        // pad for t+2 lookahead
    for (int e = tid; e < 16 * 136; e += 256)
        hs[0][e / 136][e % 136] = (_Float16)0.f;

    // this wave's B-frags: 8 x uint4 = 32 regs, loaded ONCE
    uint4 wb[4][2];
    #pragma unroll
    for (int ks = 0; ks < 4; ++ks)
        #pragma unroll
        for (int q = 0; q < 2; ++q)
            wb[ks][q] = wBg[(ks * 8 + 2 * w + q) * 64 + l];

    // prologue: xw for t=0 (float2 per row), ids for t=1
    float2 xwc[4];
    unsigned idw;
    __builtin_memcpy(&idw, &idxT[0 * 16 + 4 * g], 4);
    #pragma unroll
    for (int j = 0; j < 4; ++j) {
        int id = (idw >> (8 * j)) & 255;
        xwc[j] = *(const float2*)(xwg + id * 128 + lo * 8 + 2 * w);
    }
    __builtin_memcpy(&idw, &idxT[1 * 16 + 4 * g], 4);

    __syncthreads();

    int cur = 0;
    #pragma clang loop unroll(disable)
    for (int t = 0; t < T_; ++t) {
        // A-frags: h_{t-1} row-major (memcpy: may-alias, RAW modeled)
        half8 aF[4];
        #pragma unroll
        for (int ks = 0; ks < 4; ++ks)
            __builtin_memcpy(&aF[ks], &hs[cur][lo][ks * 32 + g * 8], 16);

        // prefetch next step's xw (global float2 x4; consumed in t+1's TAIL:
        // ~1.5 steps of slack; barrier drain at step end completes them)
        float2 xwn[4];
        #pragma unroll
        for (int j = 0; j < 4; ++j) {
            int id = (idw >> (8 * j)) & 255;
            xwn[j] = *(const float2*)(xwg + id * 128 + lo * 8 + 2 * w);
        }
        __builtin_memcpy(&idw, &idxT[(t + 2) * 16 + 4 * g], 4);

        // 8 MFMAs: acc[q] = K2F * (h @ Whh^T) for units (2w+q)*16+lo
        f32x4 acc0 = {0.f, 0.f, 0.f, 0.f}, acc1 = {0.f, 0.f, 0.f, 0.f};
        #pragma unroll
        for (int ks = 0; ks < 4; ++ks) {
            union { uint4 u; half8 h; } u0, u1;
            u0.u = wb[ks][0]; u1.u = wb[ks][1];
            acc0 = __builtin_amdgcn_mfma_f32_16x16x32_f16(aF[ks], u0.h, acc0, 0, 0, 0);
            acc1 = __builtin_amdgcn_mfma_f32_16x16x32_f16(aF[ks], u1.h, acc1, 0, 0, 0);
        }
        // tail: tanh(s) = 1 - 2/(exp2(acc + xw) + 1); 8 values/lane
        #pragma unroll
        for (int j = 0; j < 4; ++j) {
            float E0 = __builtin_amdgcn_exp2f(acc0[j] + xwc[j].x);
            float E1 = __builtin_amdgcn_exp2f(acc1[j] + xwc[j].y);
            float h0 = 1.0f - 2.0f * __builtin_amdgcn_rcpf(E0 + 1.0f);
            float h1 = 1.0f - 2.0f * __builtin_amdgcn_rcpf(E1 + 1.0f);
            hs[cur ^ 1][4 * g + j][(2 * w + 0) * 16 + lo] = (_Float16)h0;
            hs[cur ^ 1][4 * g + j][(2 * w + 1) * 16 + lo] = (_Float16)h1;
        }
        #pragma unroll
        for (int j = 0; j < 4; ++j) xwc[j] = xwn[j];
        cur ^= 1;
        __syncthreads();                       // h complete before next A-read
    }

    // fc epilogue: wave w does vocab tiles {2w, 2w+1} below V_=96 (6 tiles)
    half8 aE[4];
    #pragma unroll
    for (int ks = 0; ks < 4; ++ks)
        __builtin_memcpy(&aE[ks], &hs[cur][lo][ks * 32 + g * 8], 16);
    #pragma unroll
    for (int q = 0; q < 2; ++q) {
        const int NT = 2 * w + q;
        if (NT < 6) {
            float bf = b_fc[NT * 16 + lo];
            f32x4 acc = {bf, bf, bf, bf};
            #pragma unroll
            for (int ks = 0; ks < 4; ++ks) {
                union { uint4 u; half8 h; } ub;
                ub.u = wBfcg[(ks * 6 + NT) * 64 + l];
                acc = __builtin_amdgcn_mfma_f32_16x16x32_f16(aE[ks], ub.h, acc, 0, 0, 0);
            }
            #pragma unroll
            for (int j = 0; j < 4; ++j)
                out[(bb * 16 + 4 * g + j) * V_ + NT * 16 + lo] = acc[j];
        }
    }
}

extern "C" void kernel_launch(void* const* d_in, const int* in_sizes, int n_in,
                              void* d_out, int out_size, void* d_ws, size_t ws_size,
                              hipStream_t stream)
{
    const float* x    = (const float*)d_in[0];
    const float* W_ih = (const float*)d_in[1];
    const float* b_ih = (const float*)d_in[2];
    const float* W_hh = (const float*)d_in[3];
    const float* b_hh = (const float*)d_in[4];
    const float* W_fc = (const float*)d_in[5];
    const float* b_fc = (const float*)d_in[6];
    float* out = (float*)d_out;

    char* ws = (char*)d_ws;
    int*      idx  = (int*)ws;                               // 1 MiB
    float*    xwg  = (float*)(ws + (size_t)B_ * T_ * 4);     // 48 KiB
    _Float16* wB   = (_Float16*)((char*)xwg + V_ * H_ * 4);  // 32 KiB
    _Float16* wBfc = (_Float16*)((char*)wB + 16384 * 2);     // 24 KiB

    const int n4 = (B_ * T_ * V_) / 4;
    hipLaunchKernelGGL(onehot_idx_kernel, dim3(2048), dim3(256), 0, stream,
                       (const float4*)x, n4, idx);
    hipLaunchKernelGGL(build_xwg_kernel, dim3((V_ * H_ + 255) / 256), dim3(256),
                       0, stream, W_ih, b_ih, b_hh, xwg);
    hipLaunchKernelGGL(build_wB_kernel, dim3(64), dim3(256), 0, stream, W_hh, wB);
    hipLaunchKernelGGL(build_wBfc_kernel, dim3(48), dim3(256), 0, stream, W_fc, wBfc);
    hipLaunchKernelGGL(rnn_mfma4_kernel, dim3(B_ / 16), dim3(256), 0, stream,
                       (const uint4*)wB, (const uint4*)wBfc, xwg, idx, b_fc, out);
}